// Round 1
// baseline (144.862 us; speedup 1.0000x reference)
//
#include <hip/hip_runtime.h>

// Single fused kernel, value-partitioned by 4096-site bins (2048 bins).
// Both slice_sites (ss) and addr2site_map (a2s) are sorted, so block g owns
// site range [g*4096,(g+1)*4096) on BOTH sides:
//   1. 4 wave-parallel binary searches find e0,e1 (a2s range) and f0,f1
//      (ss range) -- independent dependent-load chains in different waves.
//   2. mark: build 128-word LDS bitmap from a2s[e0..e1) where sig>0
//      (register-merged LDS atomics, NT vec4 loads).
//   3. probe: ss[f0..f1) tested directly against the LDS bitmap, outputs
//      streamed NT to the block's contiguous slice.
// No bounds kernel, no global bitmap, no workspace, one launch.

typedef int   v4i __attribute__((ext_vector_type(4)));
typedef float v4f __attribute__((ext_vector_type(4)));

static constexpr int WORDS_PER_BIN = 128;            // 512 B bitmap slice
static constexpr int SITES_PER_BIN = 4096;           // = 2^BIN_SHIFT
static constexpr int BIN_SHIFT     = 12;
static constexpr int NBINS         = 2048;
static constexpr int BLOCK         = 256;

__device__ __forceinline__ int lower_bound_dev(
    const int* __restrict__ a, int n, int key)
{
    int lo = 0, hi = n;
    while (lo < hi) {
        const int mid = (lo + hi) >> 1;
        if (a[mid] < key) lo = mid + 1; else hi = mid;
    }
    return lo;
}

__global__ __launch_bounds__(BLOCK) void fused_kernel(
    const int* __restrict__ ss, const int* __restrict__ sig,
    const int* __restrict__ a2s, const float* __restrict__ sc,
    float* __restrict__ rem, float* __restrict__ avail,
    int n_clb, int n_slice)
{
    __shared__ unsigned int lbm[WORDS_PER_BIN];
    __shared__ int sb[4];

    const int g        = blockIdx.x;
    const int siteBase = g << BIN_SHIFT;
    const int siteEnd  = siteBase + SITES_PER_BIN;

    if (threadIdx.x < WORDS_PER_BIN) lbm[threadIdx.x] = 0u;

    // --- boundaries: one binary search per wave (chains overlap) -----------
    if ((threadIdx.x & 63) == 0) {
        const int w = threadIdx.x >> 6;
        int r;
        if      (w == 0) r = lower_bound_dev(a2s, n_clb,   siteBase);
        else if (w == 1) r = lower_bound_dev(a2s, n_clb,   siteEnd);
        else if (w == 2) r = lower_bound_dev(ss,  n_slice, siteBase);
        else             r = lower_bound_dev(ss,  n_slice, siteEnd);
        sb[w] = r;
    }
    __syncthreads();
    const int e0 = sb[0], e1 = sb[1], f0 = sb[2], f1 = sb[3];

    // --- mark: LDS bitmap from a2s/sig slice -------------------------------
    // 8 entries/thread (4 NT vec4 loads in flight). Strays outside the bin's
    // site range fail the range check (they belong to neighbor bins).
    const int mstart = e0 & ~3;
    for (int s = mstart + threadIdx.x * 8; s < e1; s += BLOCK * 8) {
        int av[8], gv[8];
        if (s + 8 <= n_clb) {
            v4i a0 = __builtin_nontemporal_load((const v4i*)(a2s + s));
            v4i a1 = __builtin_nontemporal_load((const v4i*)(a2s + s + 4));
            v4i g0 = __builtin_nontemporal_load((const v4i*)(sig + s));
            v4i g1 = __builtin_nontemporal_load((const v4i*)(sig + s + 4));
            av[0]=a0.x; av[1]=a0.y; av[2]=a0.z; av[3]=a0.w;
            av[4]=a1.x; av[5]=a1.y; av[6]=a1.z; av[7]=a1.w;
            gv[0]=g0.x; gv[1]=g0.y; gv[2]=g0.z; gv[3]=g0.w;
            gv[4]=g1.x; gv[5]=g1.y; gv[6]=g1.z; gv[7]=g1.w;
        } else {
#pragma unroll
            for (int j = 0; j < 8; ++j) {
                const int i = s + j;
                const bool ok = i < n_clb;
                av[j] = ok ? a2s[i] : -1;
                gv[j] = ok ? sig[i] : 0;
            }
        }
        unsigned int curw = 0xFFFFFFFFu, curm = 0u;
#pragma unroll
        for (int j = 0; j < 8; ++j) {
            const int site = av[j];
            if (gv[j] > 0 && site >= siteBase && site < siteEnd) {
                const unsigned int u = (unsigned int)(site - siteBase);
                const unsigned int w = u >> 5;
                const unsigned int m = 1u << (u & 31u);
                if (w == curw) curm |= m;
                else { if (curm) atomicOr(&lbm[curw], curm); curw = w; curm = m; }
            }
        }
        if (curm) atomicOr(&lbm[curw], curm);
    }

    __syncthreads();

    // --- probe: ss[f0..f1) against LDS bitmap, contiguous output slice -----
    const int fa = (f0 + 3) & ~3;          // first vec4-aligned index
    const int fb = f1 & ~3;                // end of vec4 region
    const int head_end = fa < f1 ? fa : f1;

    // scalar head (<=3 elements)
    {
        const int i = f0 + (int)threadIdx.x;
        if (i < head_end) {
            const unsigned int u   = (unsigned int)(ss[i] - siteBase);
            const unsigned int bit = (lbm[u >> 5] >> (u & 31u)) & 1u;
            rem[i]   = bit ? 0.0f : 1.0f;
            avail[i] = bit ? 0.0f : sc[i];
        }
    }
    // vec4 body
    if (fa < fb) {
        for (int q = fa / 4 + (int)threadIdx.x; q < fb / 4; q += BLOCK) {
            v4i s = __builtin_nontemporal_load((const v4i*)ss + q);
            v4f f = __builtin_nontemporal_load((const v4f*)sc + q);
            v4f r, a;
#pragma unroll
            for (int j = 0; j < 4; ++j) {
                const unsigned int u   = (unsigned int)(s[j] - siteBase);
                const unsigned int bit = (lbm[u >> 5] >> (u & 31u)) & 1u;
                r[j] = bit ? 0.0f : 1.0f;
                a[j] = bit ? 0.0f : f[j];
            }
            __builtin_nontemporal_store(r, (v4f*)rem + q);
            __builtin_nontemporal_store(a, (v4f*)avail + q);
        }
    }
    // scalar tail (<=3 elements)
    {
        const int tstart = fb > head_end ? fb : head_end;
        const int i = tstart + (int)threadIdx.x;
        if (i < f1) {
            const unsigned int u   = (unsigned int)(ss[i] - siteBase);
            const unsigned int bit = (lbm[u >> 5] >> (u & 31u)) & 1u;
            rem[i]   = bit ? 0.0f : 1.0f;
            avail[i] = bit ? 0.0f : sc[i];
        }
    }
}

extern "C" void kernel_launch(void* const* d_in, const int* in_sizes, int n_in,
                              void* d_out, int out_size, void* d_ws, size_t ws_size,
                              hipStream_t stream) {
    const int*   ss  = (const int*)d_in[0];
    const int*   sig = (const int*)d_in[1];
    const int*   a2s = (const int*)d_in[2];
    const float* sc  = (const float*)d_in[3];
    const int n_slice = in_sizes[0];
    const int n_clb   = in_sizes[1];

    float* rem   = (float*)d_out;
    float* avail = rem + n_slice;

    fused_kernel<<<NBINS, BLOCK, 0, stream>>>(ss, sig, a2s, sc, rem, avail,
                                              n_clb, n_slice);
}